// Round 1
// baseline (163.046 us; speedup 1.0000x reference)
//
#include <hip/hip_runtime.h>
#include <hip/hip_bf16.h>

#ifndef __has_builtin
#define __has_builtin(x) 0
#endif

// exp2 and rcp on the fast transcendental pipe (v_exp_f32 / v_rcp_f32)
__device__ __forceinline__ float fast_exp2(float x) {
#if __has_builtin(__builtin_amdgcn_exp2f)
  return __builtin_amdgcn_exp2f(x);
#else
  return exp2f(x);
#endif
}
__device__ __forceinline__ float fast_rcp(float x) {
#if __has_builtin(__builtin_amdgcn_rcpf)
  return __builtin_amdgcn_rcpf(x);
#else
  return 1.0f / x;
#endif
}

constexpr int Bsz = 8, QL = 128, KL = 512, DD = 256, UU = 256;
constexpr int QB = 4;                    // q rows per block in attn kernel
constexpr float NEG_INF = -1e6f;
constexpr float C2 = 2.885390081777927f; // 2*log2(e): exp2(C2*x) == exp(2x)

// ---------------------------------------------------------------------------
// Kernel 1: projections, pre-scaled by C2.
//   qp[b][q][u]  = C2 * sum_d query[b,q,d] * Wq[d,u]         ([B,Q,U] layout)
//   kpT[b][u][k] = C2 * sum_d key[b,k,d]   * Wk[d,u]         ([B,U,K] layout!)
// One block per 4 rows; thread = u. Input-row loads are wave-uniform (s_load),
// W loads coalesced across lanes. kpT stores: 4 consecutive k per thread ->
// float4 store (scattered across lanes but L2-absorbed, ~4MB total).
// ---------------------------------------------------------------------------
__global__ __launch_bounds__(256) void proj_kernel(
    const float* __restrict__ query, const float* __restrict__ key,
    const float* __restrict__ Wq, const float* __restrict__ Wk,
    float* __restrict__ qp, float* __restrict__ kpT)
{
  const int u   = threadIdx.x;
  const int blk = blockIdx.x;
  const bool isQ = blk < (Bsz * QL / 4);
  const int  m0  = isQ ? blk * 4 : (blk - Bsz * QL / 4) * 4;
  const float* __restrict__ in = isQ ? query : key;
  const float* __restrict__ W  = isQ ? Wq : Wk;
  const float* r0 = in + (size_t)m0 * DD;

  float acc0 = 0.f, acc1 = 0.f, acc2 = 0.f, acc3 = 0.f;
  for (int d = 0; d < DD; d += 4) {
    const float4 qa = *reinterpret_cast<const float4*>(r0 + d);
    const float4 qb = *reinterpret_cast<const float4*>(r0 + DD + d);
    const float4 qc = *reinterpret_cast<const float4*>(r0 + 2 * DD + d);
    const float4 qd = *reinterpret_cast<const float4*>(r0 + 3 * DD + d);
    const float w0 = W[(d + 0) * UU + u];
    const float w1 = W[(d + 1) * UU + u];
    const float w2 = W[(d + 2) * UU + u];
    const float w3 = W[(d + 3) * UU + u];
    acc0 = fmaf(qa.x, w0, fmaf(qa.y, w1, fmaf(qa.z, w2, fmaf(qa.w, w3, acc0))));
    acc1 = fmaf(qb.x, w0, fmaf(qb.y, w1, fmaf(qb.z, w2, fmaf(qb.w, w3, acc1))));
    acc2 = fmaf(qc.x, w0, fmaf(qc.y, w1, fmaf(qc.z, w2, fmaf(qc.w, w3, acc2))));
    acc3 = fmaf(qd.x, w0, fmaf(qd.y, w1, fmaf(qd.z, w2, fmaf(qd.w, w3, acc3))));
  }
  if (isQ) {
    float* o = qp + (size_t)m0 * UU + u;
    o[0]      = acc0 * C2;
    o[UU]     = acc1 * C2;
    o[2 * UU] = acc2 * C2;
    o[3 * UU] = acc3 * C2;
  } else {
    const int b = m0 / KL, k0 = m0 % KL;
    float* o = kpT + ((size_t)b * UU + u) * KL + k0;
    *reinterpret_cast<float4*>(o) = make_float4(acc0 * C2, acc1 * C2, acc2 * C2, acc3 * C2);
  }
}

// ---------------------------------------------------------------------------
// Kernel 2: scores (tanh contraction) + masked softmax + attn@V.
// Block = (b, 4 q-rows), 256 threads. Thread t owns k = {2t, 2t+1}.
// score[q][k] = Vsum - sum_u 2*v_w[u] * rcp(1 + exp2(qp_c[q][u] + kpT_c[u][k]))
// kpT loads coalesced float2; qp & 2*v_w broadcast from LDS; accumulation
// fully in-register (no cross-lane reduce in the hot loop).
// ---------------------------------------------------------------------------
__global__ __launch_bounds__(256) void attn_kernel(
    const float* __restrict__ value, const int* __restrict__ valid_len,
    const float* __restrict__ v_w, const float* __restrict__ qp,
    const float* __restrict__ kpT, float* __restrict__ out)
{
  __shared__ __align__(16) float sc[QB][KL];   // attn weights (8 KB)
  __shared__ float qp_s[QB][UU];               // 4 KB
  __shared__ float w2_s[UU];                   // 1 KB
  __shared__ float red_s[4][QB];               // cross-wave reduce scratch

  const int t    = threadIdx.x;
  const int lane = t & 63, wave = t >> 6;
  const int blk  = blockIdx.x;
  const int b    = blk / (QL / QB);
  const int q0   = (blk % (QL / QB)) * QB;

  // ---- stage qp rows + 2*v_w into LDS; block-reduce Vsum = sum(v_w) ----
  const float vw = v_w[t];
  w2_s[t] = 2.0f * vw;
#pragma unroll
  for (int q = 0; q < QB; ++q)
    qp_s[q][t] = qp[(size_t)(b * QL + q0 + q) * UU + t];

  float s = vw;
#pragma unroll
  for (int off = 32; off >= 1; off >>= 1) s += __shfl_xor(s, off, 64);
  if (lane == 0) red_s[wave][0] = s;
  __syncthreads();
  const float vsum = red_s[0][0] + red_s[1][0] + red_s[2][0] + red_s[3][0];
  __syncthreads();

  // ---- score accumulation over u ----
  float acc[QB][2];
#pragma unroll
  for (int q = 0; q < QB; ++q) { acc[q][0] = 0.f; acc[q][1] = 0.f; }

  const float2* __restrict__ kp2 =
      reinterpret_cast<const float2*>(kpT + (size_t)b * UU * KL);
#pragma unroll 2
  for (int u = 0; u < UU; ++u) {
    const float2 kv = kp2[u * (KL / 2) + t];
    const float w2 = w2_s[u];
#pragma unroll
    for (int q = 0; q < QB; ++q) {
      const float qv = qp_s[q][u];
      const float e0 = fast_exp2(qv + kv.x);   // = exp(2x), x = qp+kp (pre-scaled)
      const float e1 = fast_exp2(qv + kv.y);
      const float r0 = fast_rcp(1.0f + e0);    // tanh(x) = 1 - 2*r
      const float r1 = fast_rcp(1.0f + e1);
      acc[q][0] = fmaf(w2, r0, acc[q][0]);
      acc[q][1] = fmaf(w2, r1, acc[q][1]);
    }
  }

  // ---- mask + softmax over k (512 entries, spread 2/thread) ----
  const int vlen = valid_len[b];
  const int k2 = 2 * t;
  float sr[QB][2], lmax[QB];
#pragma unroll
  for (int q = 0; q < QB; ++q) {
    sr[q][0] = (k2     < vlen) ? (vsum - acc[q][0]) : NEG_INF;
    sr[q][1] = (k2 + 1 < vlen) ? (vsum - acc[q][1]) : NEG_INF;
    lmax[q] = fmaxf(sr[q][0], sr[q][1]);
  }
#pragma unroll
  for (int off = 32; off >= 1; off >>= 1) {
#pragma unroll
    for (int q = 0; q < QB; ++q)
      lmax[q] = fmaxf(lmax[q], __shfl_xor(lmax[q], off, 64));
  }
  if (lane == 0) {
#pragma unroll
    for (int q = 0; q < QB; ++q) red_s[wave][q] = lmax[q];
  }
  __syncthreads();
  float mq[QB];
#pragma unroll
  for (int q = 0; q < QB; ++q)
    mq[q] = fmaxf(fmaxf(red_s[0][q], red_s[1][q]), fmaxf(red_s[2][q], red_s[3][q]));
  __syncthreads();

  float ex[QB][2], lsum[QB];
#pragma unroll
  for (int q = 0; q < QB; ++q) {
    ex[q][0] = __expf(sr[q][0] - mq[q]);   // masked -> exp(~-1e6) -> 0, same as ref
    ex[q][1] = __expf(sr[q][1] - mq[q]);
    lsum[q] = ex[q][0] + ex[q][1];
  }
#pragma unroll
  for (int off = 32; off >= 1; off >>= 1) {
#pragma unroll
    for (int q = 0; q < QB; ++q) lsum[q] += __shfl_xor(lsum[q], off, 64);
  }
  if (lane == 0) {
#pragma unroll
    for (int q = 0; q < QB; ++q) red_s[wave][q] = lsum[q];
  }
  __syncthreads();
#pragma unroll
  for (int q = 0; q < QB; ++q) {
    const float tot = red_s[0][q] + red_s[1][q] + red_s[2][q] + red_s[3][q];
    const float inv = fast_rcp(tot);         // tot >= 1 always (max term = 1)
    sc[q][k2]     = ex[q][0] * inv;
    sc[q][k2 + 1] = ex[q][1] * inv;
  }
  __syncthreads();

  // ---- out[b,q,d] = sum_k attn[q][k] * value[b,k,d]; thread = d ----
  const float* __restrict__ vb = value + (size_t)b * KL * DD;
  float ov[QB] = {0.f, 0.f, 0.f, 0.f};
  for (int k = 0; k < KL; k += 4) {
    const float v0 = vb[(k + 0) * DD + t];
    const float v1 = vb[(k + 1) * DD + t];
    const float v2 = vb[(k + 2) * DD + t];
    const float v3 = vb[(k + 3) * DD + t];
#pragma unroll
    for (int q = 0; q < QB; ++q) {
      const float4 a = *reinterpret_cast<const float4*>(&sc[q][k]);
      ov[q] = fmaf(a.x, v0, fmaf(a.y, v1, fmaf(a.z, v2, fmaf(a.w, v3, ov[q]))));
    }
  }
#pragma unroll
  for (int q = 0; q < QB; ++q)
    out[(size_t)(b * QL + q0 + q) * DD + t] = ov[q];
}

extern "C" void kernel_launch(void* const* d_in, const int* in_sizes, int n_in,
                              void* d_out, int out_size, void* d_ws, size_t ws_size,
                              hipStream_t stream) {
  const float* query     = (const float*)d_in[0];
  const float* key       = (const float*)d_in[1];
  const float* value     = (const float*)d_in[2];
  const int*   valid_len = (const int*)d_in[3];
  const float* Wq        = (const float*)d_in[4];
  const float* Wk        = (const float*)d_in[5];
  const float* v_w       = (const float*)d_in[6];
  float* out = (float*)d_out;

  float* qp  = (float*)d_ws;                       // B*QL*UU floats (1 MB)
  float* kpT = qp + (size_t)Bsz * QL * UU;         // B*UU*KL floats (4 MB)

  const int proj_blocks = Bsz * QL / 4 + Bsz * KL / 4;  // 256 + 1024
  proj_kernel<<<proj_blocks, 256, 0, stream>>>(query, key, Wq, Wk, qp, kpT);

  const int attn_blocks = Bsz * (QL / QB);              // 256
  attn_kernel<<<attn_blocks, 256, 0, stream>>>(value, valid_len, v_w, qp, kpT, out);
}